// Round 1
// baseline (4047.985 us; speedup 1.0000x reference)
//
#include <hip/hip_runtime.h>

#define NIN 64
#define NOUT 32
#define KK 9

// ---------------------------------------------------------------------------
// Kernel 1: initialize every output row with the bias (folds bias into the
// accumulation base; also clears the 0xAA poison).
// out is [num_out, 32] fp32 -> out_size/4 float4s, bias is 8 float4s.
__global__ void mink_init_bias(float4* __restrict__ out,
                               const float4* __restrict__ bias, int n4) {
    int i = blockIdx.x * blockDim.x + threadIdx.x;
    if (i < n4) {
        out[i] = bias[i & 7];  // 32 floats per row == 8 float4 per row
    }
}

// ---------------------------------------------------------------------------
// Kernel 2: one thread per input site n.
//   - loads x[64] into VGPRs (feats read exactly once, 16x dwordx4)
//   - for each of the 9 kernel offsets: 64x32 FMA into 32 accumulators,
//     weights read with wave-uniform addresses (-> scalar loads, K$-resident)
//   - 32 native fp32 atomics into the mapped output row
__global__ __launch_bounds__(256) void mink_scatter(
    const float* __restrict__ feats,
    const float* __restrict__ weight,   // [9, 64, 32]
    const int* __restrict__ out_idx,    // [N, 9]
    float* __restrict__ out,            // [num_out, 32]
    int n) {
    int nidx = blockIdx.x * blockDim.x + threadIdx.x;
    if (nidx >= n) return;

    float x[NIN];
    const float4* f4 = reinterpret_cast<const float4*>(feats + (size_t)nidx * NIN);
    #pragma unroll
    for (int j = 0; j < NIN / 4; ++j) {
        float4 v = f4[j];
        x[j * 4 + 0] = v.x;
        x[j * 4 + 1] = v.y;
        x[j * 4 + 2] = v.z;
        x[j * 4 + 3] = v.w;
    }

    // out_idx row for this n
    const int* idx = out_idx + (size_t)nidx * KK;

    for (int k = 0; k < KK; ++k) {
        int row = idx[k];
        const float* wk = weight + k * (NIN * NOUT);

        float acc[NOUT];
        #pragma unroll
        for (int d = 0; d < NOUT; ++d) acc[d] = 0.0f;

        #pragma unroll 4
        for (int c = 0; c < NIN; ++c) {
            float xc = x[c];
            #pragma unroll
            for (int d = 0; d < NOUT; ++d) {
                acc[d] = fmaf(xc, wk[c * NOUT + d], acc[d]);
            }
        }

        float* orow = out + (size_t)row * NOUT;
        #pragma unroll
        for (int d = 0; d < NOUT; ++d) {
            unsafeAtomicAdd(orow + d, acc[d]);
        }
    }
}

// ---------------------------------------------------------------------------
// Kernel 3: ReLU pass over the whole output.
__global__ void mink_relu(float4* __restrict__ out, int n4) {
    int i = blockIdx.x * blockDim.x + threadIdx.x;
    if (i < n4) {
        float4 v = out[i];
        v.x = fmaxf(v.x, 0.0f);
        v.y = fmaxf(v.y, 0.0f);
        v.z = fmaxf(v.z, 0.0f);
        v.w = fmaxf(v.w, 0.0f);
        out[i] = v;
    }
}

extern "C" void kernel_launch(void* const* d_in, const int* in_sizes, int n_in,
                              void* d_out, int out_size, void* d_ws, size_t ws_size,
                              hipStream_t stream) {
    const float* feats  = (const float*)d_in[0];  // [N, 64] f32
    const float* weight = (const float*)d_in[1];  // [9, 64, 32] f32
    const float* bias   = (const float*)d_in[2];  // [32] f32
    const int*   oidx   = (const int*)d_in[3];    // [N, 9] i32
    float* out = (float*)d_out;                   // [num_out, 32] f32

    int n   = in_sizes[0] / NIN;   // 262144
    int n4  = out_size / 4;        // float4 count of output

    mink_init_bias<<<(n4 + 255) / 256, 256, 0, stream>>>(
        (float4*)out, (const float4*)bias, n4);

    mink_scatter<<<(n + 255) / 256, 256, 0, stream>>>(
        feats, weight, oidx, out, n);

    mink_relu<<<(n4 + 255) / 256, 256, 0, stream>>>((float4*)out, n4);
}

// Round 2
// 4019.062 us; speedup vs baseline: 1.0072x; 1.0072x over previous
//
#include <hip/hip_runtime.h>

#define NIN 64
#define NOUT 32
#define KK 9

// ---------------------------------------------------------------------------
// Kernel 1: initialize every output row with the bias (folds bias into the
// accumulation base; also clears the 0xAA poison).
__global__ void mink_init_bias(float4* __restrict__ out,
                               const float4* __restrict__ bias, int n4) {
    int i = blockIdx.x * blockDim.x + threadIdx.x;
    if (i < n4) {
        out[i] = bias[i & 7];  // 32 floats per row == 8 float4 per row
    }
}

// ---------------------------------------------------------------------------
// Kernel 2: one thread per input site n.
//   x[64] and acc[32] FULLY unrolled -> all compile-time indices -> VGPRs
//   (round-1 bug: partial unroll made x[] runtime-indexed -> scratch spill,
//    2.4 GB of HBM scratch traffic). k-loop kept rolled so the body (~2048
//   FMAs ~ 16 KB) stays I$-resident.
__global__ __launch_bounds__(256) void mink_scatter(
    const float* __restrict__ feats,
    const float* __restrict__ weight,   // [9, 64, 32]
    const int* __restrict__ out_idx,    // [N, 9]
    float* __restrict__ out,            // [num_out, 32]
    int n) {
    int nidx = blockIdx.x * blockDim.x + threadIdx.x;
    if (nidx >= n) return;

    float x[NIN];
    const float4* f4 = reinterpret_cast<const float4*>(feats + (size_t)nidx * NIN);
    #pragma unroll
    for (int j = 0; j < NIN / 4; ++j) {
        float4 v = f4[j];
        x[j * 4 + 0] = v.x;
        x[j * 4 + 1] = v.y;
        x[j * 4 + 2] = v.z;
        x[j * 4 + 3] = v.w;
    }

    const int* idx = out_idx + (size_t)nidx * KK;

    #pragma unroll 1
    for (int k = 0; k < KK; ++k) {
        int row = idx[k];
        const float* wk = weight + k * (NIN * NOUT);

        float acc[NOUT];
        #pragma unroll
        for (int d = 0; d < NOUT; ++d) acc[d] = 0.0f;

        #pragma unroll    // FULL unroll: x[c] index must be compile-time
        for (int c = 0; c < NIN; ++c) {
            float xc = x[c];
            #pragma unroll
            for (int d = 0; d < NOUT; ++d) {
                acc[d] = fmaf(xc, wk[c * NOUT + d], acc[d]);
            }
        }

        float* orow = out + (size_t)row * NOUT;
        #pragma unroll
        for (int d = 0; d < NOUT; ++d) {
            unsafeAtomicAdd(orow + d, acc[d]);
        }
    }
}

// ---------------------------------------------------------------------------
// Kernel 3: ReLU pass over the whole output.
__global__ void mink_relu(float4* __restrict__ out, int n4) {
    int i = blockIdx.x * blockDim.x + threadIdx.x;
    if (i < n4) {
        float4 v = out[i];
        v.x = fmaxf(v.x, 0.0f);
        v.y = fmaxf(v.y, 0.0f);
        v.z = fmaxf(v.z, 0.0f);
        v.w = fmaxf(v.w, 0.0f);
        out[i] = v;
    }
}

extern "C" void kernel_launch(void* const* d_in, const int* in_sizes, int n_in,
                              void* d_out, int out_size, void* d_ws, size_t ws_size,
                              hipStream_t stream) {
    const float* feats  = (const float*)d_in[0];  // [N, 64] f32
    const float* weight = (const float*)d_in[1];  // [9, 64, 32] f32
    const float* bias   = (const float*)d_in[2];  // [32] f32
    const int*   oidx   = (const int*)d_in[3];    // [N, 9] i32
    float* out = (float*)d_out;                   // [num_out, 32] f32

    int n   = in_sizes[0] / NIN;   // 262144
    int n4  = out_size / 4;        // float4 count of output

    mink_init_bias<<<(n4 + 255) / 256, 256, 0, stream>>>(
        (float4*)out, (const float4*)bias, n4);

    mink_scatter<<<(n + 255) / 256, 256, 0, stream>>>(
        feats, weight, oidx, out, n);

    mink_relu<<<(n4 + 255) / 256, 256, 0, stream>>>((float4*)out, n4);
}

// Round 3
// 543.639 us; speedup vs baseline: 7.4461x; 7.3929x over previous
//
#include <hip/hip_runtime.h>

#define NIN 64
#define NOUT 32
#define KK 9
#define NSITES 4   // input sites per 32-thread group

// ---------------------------------------------------------------------------
// Kernel 1: initialize every output row with the bias (folds bias, clears
// the 0xAA poison).
__global__ void mink_init_bias(float4* __restrict__ out,
                               const float4* __restrict__ bias, int n4) {
    int i = blockIdx.x * blockDim.x + threadIdx.x;
    if (i < n4) {
        out[i] = bias[i & 7];  // 32 floats per row == 8 float4 per row
    }
}

// ---------------------------------------------------------------------------
// Kernel 2: thread = (site-group g, output channel d). Lanes 0-31 of a wave
// share one group (d = 0..31), lanes 32-63 the next group. Each group handles
// NSITES consecutive input sites.
//   - weights (72 KB) staged in LDS once per block; ds_read per (k,c) is
//     conflict-free (lanes 0-31 -> banks 0-31; lanes 32-63 broadcast).
//   - atomics: one instruction writes 32 consecutive channels of a row ->
//     2 rows x 2 lines = 4 lines per wave-instr (vs 64 in round 2).
__global__ __launch_bounds__(256) void mink_scatter(
    const float* __restrict__ feats,     // [N, 64]
    const float4* __restrict__ weight4,  // [9*64*32/4]
    const int* __restrict__ out_idx,     // [N, 9]
    float* __restrict__ out,             // [num_out, 32]
    int ngroups) {
    __shared__ float wlds[KK * NIN * NOUT];  // 72 KB
    {
        float4* wl4 = (float4*)wlds;
        for (int i = threadIdx.x; i < KK * NIN * NOUT / 4; i += 256)
            wl4[i] = weight4[i];
    }
    __syncthreads();

    int t = blockIdx.x * 256 + threadIdx.x;
    int g = t >> 5;        // 32-thread group id
    int d = t & 31;        // output channel
    if (g >= ngroups) return;
    int n0 = g * NSITES;

    float acc[NSITES][KK];
    #pragma unroll
    for (int s = 0; s < NSITES; ++s)
        #pragma unroll
        for (int k = 0; k < KK; ++k) acc[s][k] = 0.0f;

    const float4* f4 = reinterpret_cast<const float4*>(feats) + (size_t)n0 * (NIN / 4);

    #pragma unroll 4
    for (int c4 = 0; c4 < NIN / 4; ++c4) {
        // broadcast loads of the 4 sites' next 4 features (same addr across
        // the 32-lane group -> single request)
        float xsf[NSITES][4];
        #pragma unroll
        for (int s = 0; s < NSITES; ++s) {
            float4 v = f4[s * (NIN / 4) + c4];
            xsf[s][0] = v.x; xsf[s][1] = v.y; xsf[s][2] = v.z; xsf[s][3] = v.w;
        }
        #pragma unroll
        for (int j = 0; j < 4; ++j) {
            int c = c4 * 4 + j;
            #pragma unroll
            for (int k = 0; k < KK; ++k) {
                float w = wlds[(k * NIN + c) * NOUT + d];
                #pragma unroll
                for (int s = 0; s < NSITES; ++s)
                    acc[s][k] = fmaf(xsf[s][j], w, acc[s][k]);
            }
        }
    }

    // coalesced scatter: 32 lanes -> 32 consecutive channels of one row
    const int* idx = out_idx + (size_t)n0 * KK;
    #pragma unroll
    for (int s = 0; s < NSITES; ++s) {
        #pragma unroll
        for (int k = 0; k < KK; ++k) {
            int row = idx[s * KK + k];   // broadcast load within group
            unsafeAtomicAdd(out + (size_t)row * NOUT + d, acc[s][k]);
        }
    }
}

// ---------------------------------------------------------------------------
// Kernel 3: ReLU pass over the whole output.
__global__ void mink_relu(float4* __restrict__ out, int n4) {
    int i = blockIdx.x * blockDim.x + threadIdx.x;
    if (i < n4) {
        float4 v = out[i];
        v.x = fmaxf(v.x, 0.0f);
        v.y = fmaxf(v.y, 0.0f);
        v.z = fmaxf(v.z, 0.0f);
        v.w = fmaxf(v.w, 0.0f);
        out[i] = v;
    }
}

extern "C" void kernel_launch(void* const* d_in, const int* in_sizes, int n_in,
                              void* d_out, int out_size, void* d_ws, size_t ws_size,
                              hipStream_t stream) {
    const float* feats  = (const float*)d_in[0];  // [N, 64] f32
    const float* weight = (const float*)d_in[1];  // [9, 64, 32] f32
    const float* bias   = (const float*)d_in[2];  // [32] f32
    const int*   oidx   = (const int*)d_in[3];    // [N, 9] i32
    float* out = (float*)d_out;                   // [num_out, 32] f32

    int n  = in_sizes[0] / NIN;   // 262144
    int n4 = out_size / 4;        // float4 count of output

    mink_init_bias<<<(n4 + 255) / 256, 256, 0, stream>>>(
        (float4*)out, (const float4*)bias, n4);

    int ngroups = n / NSITES;                 // 65536 (N divisible by 4)
    int nthreads = ngroups * 32;              // 2,097,152
    mink_scatter<<<nthreads / 256, 256, 0, stream>>>(
        feats, (const float4*)weight, oidx, out, ngroups);

    mink_relu<<<(n4 + 255) / 256, 256, 0, stream>>>((float4*)out, n4);
}

// Round 4
// 307.561 us; speedup vs baseline: 13.1616x; 1.7676x over previous
//
#include <hip/hip_runtime.h>

#define NIN 64
#define NOUT 32
#define KK 9

typedef __attribute__((ext_vector_type(8))) short bf16x8;
typedef __attribute__((ext_vector_type(16))) float f32x16;

// fp32 -> bf16 round-to-nearest-even (3 VALU)
__device__ __forceinline__ unsigned short f2bf_rne(float f) {
    unsigned int u = __builtin_bit_cast(unsigned int, f);
    unsigned int r = (u + 0x7FFFu + ((u >> 16) & 1u)) >> 16;
    return (unsigned short)r;
}
__device__ __forceinline__ float bf2f(unsigned short h) {
    unsigned int u = ((unsigned int)h) << 16;
    return __builtin_bit_cast(float, u);
}

// ---------------------------------------------------------------------------
// Kernel 0: pre-pack weights into MFMA B-fragment layout, split bf16 hi/lo.
// wf[(k*4+ks)*64 + lane][j] = bf16(W[k][ ks*16 + (lane>>5)*4 + (j&3) + 8*(j>>2) ][ lane&31 ])
// (concatenated K-halves convention for gfx950 doubled-K MFMAs)
__global__ void mink_prep_w(const float* __restrict__ w,
                            unsigned short* __restrict__ wf) {
    int t = blockIdx.x * 256 + threadIdx.x;
    if (t >= KK * 4 * 64) return;
    int l = t & 63, ks = (t >> 6) & 3, k = t >> 8;
    int col = l & 31;
    int kb = ks * 16 + (l >> 5) * 4;
    #pragma unroll
    for (int j = 0; j < 8; ++j) {
        int c = kb + (j & 3) + 8 * (j >> 2);
        float v = w[(k * NIN + c) * NOUT + col];
        unsigned short hi = f2bf_rne(v);
        unsigned short lo = f2bf_rne(v - bf2f(hi));
        wf[(size_t)((k * 4 + ks) * 64 + l) * 8 + j] = hi;
        wf[(size_t)(KK * 4 * 64 * 8) + (size_t)((k * 4 + ks) * 64 + l) * 8 + j] = lo;
    }
}

// ---------------------------------------------------------------------------
// Kernel 1: initialize every output row with the bias (folds bias, clears
// the 0xAA poison).
__global__ void mink_init_bias(float4* __restrict__ out,
                               const float4* __restrict__ bias, int n4) {
    int i = blockIdx.x * blockDim.x + threadIdx.x;
    if (i < n4) {
        out[i] = bias[i & 7];
    }
}

// ---------------------------------------------------------------------------
// Kernel 2: one wave per 32-site tile. Split-bf16 MFMA (3 terms) computes
// the 32x32 contribution tile per kernel offset k; scatter via full-line
// atomics (2 rows x 128B per wave-instr). No LDS.
__global__ __launch_bounds__(256) void mink_scatter_mfma(
    const float* __restrict__ feats,       // [N, 64] f32
    const unsigned short* __restrict__ wf, // packed bf16 frags (hi, lo)
    const int* __restrict__ out_idx,       // [N, 9]
    float* __restrict__ out,               // [num_out, 32]
    int ntiles) {
    int wid  = (blockIdx.x * 256 + threadIdx.x) >> 6;  // tile id
    int lane = threadIdx.x & 63;
    if (wid >= ntiles) return;
    int n0   = wid * 32;
    int half = lane >> 5;
    int col  = lane & 31;

    // ---- A fragments: load fp32 feats, convert to split bf16 in-register.
    // A row = lane&31 (site), frag elem j -> chan = ks*16 + half*4 + (j&3) + 8*(j>>2)
    const float* xrow = feats + (size_t)(n0 + col) * NIN;
    int kbase = half * 4;
    bf16x8 ahi[4], alo[4];
    #pragma unroll
    for (int ks = 0; ks < 4; ++ks) {
        float4 v0 = *(const float4*)(xrow + ks * 16 + kbase);
        float4 v1 = *(const float4*)(xrow + ks * 16 + kbase + 8);
        float xs[8] = {v0.x, v0.y, v0.z, v0.w, v1.x, v1.y, v1.z, v1.w};
        #pragma unroll
        for (int j = 0; j < 8; ++j) {
            unsigned short h = f2bf_rne(xs[j]);
            ahi[ks][j] = (short)h;
            alo[ks][j] = (short)f2bf_rne(xs[j] - bf2f(h));
        }
    }

    const bf16x8* wfh = (const bf16x8*)wf;            // [(k*4+ks)*64 + lane]
    const bf16x8* wfl = wfh + KK * 4 * 64;

    #pragma unroll 1
    for (int k = 0; k < KK; ++k) {
        f32x16 acc = {0,0,0,0,0,0,0,0,0,0,0,0,0,0,0,0};
        #pragma unroll
        for (int ks = 0; ks < 4; ++ks) {
            bf16x8 bh = wfh[(k * 4 + ks) * 64 + lane];
            bf16x8 bl = wfl[(k * 4 + ks) * 64 + lane];
            acc = __builtin_amdgcn_mfma_f32_32x32x16_bf16(ahi[ks], bh, acc, 0, 0, 0);
            acc = __builtin_amdgcn_mfma_f32_32x32x16_bf16(ahi[ks], bl, acc, 0, 0, 0);
            acc = __builtin_amdgcn_mfma_f32_32x32x16_bf16(alo[ks], bh, acc, 0, 0, 0);
        }
        // scatter: C/D layout col=lane&31, row=(r&3)+8*(r>>2)+4*half (site)
        #pragma unroll
        for (int r = 0; r < 16; ++r) {
            int site = (r & 3) + 8 * (r >> 2) + 4 * half;
            int row = out_idx[(size_t)(n0 + site) * KK + k];  // 2-addr broadcast
            unsafeAtomicAdd(out + (size_t)row * NOUT + col, acc[r]);
        }
    }
}

// ---------------------------------------------------------------------------
// Kernel 3: ReLU pass over the whole output.
__global__ void mink_relu(float4* __restrict__ out, int n4) {
    int i = blockIdx.x * blockDim.x + threadIdx.x;
    if (i < n4) {
        float4 v = out[i];
        v.x = fmaxf(v.x, 0.0f);
        v.y = fmaxf(v.y, 0.0f);
        v.z = fmaxf(v.z, 0.0f);
        v.w = fmaxf(v.w, 0.0f);
        out[i] = v;
    }
}

extern "C" void kernel_launch(void* const* d_in, const int* in_sizes, int n_in,
                              void* d_out, int out_size, void* d_ws, size_t ws_size,
                              hipStream_t stream) {
    const float* feats  = (const float*)d_in[0];  // [N, 64] f32
    const float* weight = (const float*)d_in[1];  // [9, 64, 32] f32
    const float* bias   = (const float*)d_in[2];  // [32] f32
    const int*   oidx   = (const int*)d_in[3];    // [N, 9] i32
    float* out = (float*)d_out;                   // [num_out, 32] f32
    unsigned short* wf = (unsigned short*)d_ws;   // 73728 B: bf16 hi+lo frags

    int n  = in_sizes[0] / NIN;   // 262144
    int n4 = out_size / 4;        // float4 count of output

    mink_prep_w<<<(KK * 4 * 64 + 255) / 256, 256, 0, stream>>>(weight, wf);

    mink_init_bias<<<(n4 + 255) / 256, 256, 0, stream>>>(
        (float4*)out, (const float4*)bias, n4);

    int ntiles = n / 32;                       // 8192
    int nblocks = ntiles * 64 / 256;           // 2048 (4 waves/block)
    mink_scatter_mfma<<<nblocks, 256, 0, stream>>>(feats, wf, oidx, out, ntiles);

    mink_relu<<<(n4 + 255) / 256, 256, 0, stream>>>((float4*)out, n4);
}